// Round 7
// baseline (242.245 us; speedup 1.0000x reference)
//
#include <hip/hip_runtime.h>
#include <math.h>

#define NQ 22
#define DIM (1u << NQ)

typedef float v2f __attribute__((ext_vector_type(2)));

// ---------------- fused gate matrices: U = RZ * RY * RX, fp64 -> fp32 ----------------
__global__ void k_gates(const float* __restrict__ params, float* __restrict__ U) {
  int t = blockIdx.x * blockDim.x + threadIdx.x;
  if (t >= 88) return;               // t = l*22 + q
  const float* p = params + t * 3;
  double hx = 0.5 * (double)p[0], hy = 0.5 * (double)p[1], hz = 0.5 * (double)p[2];
  double cx = cos(hx), sx = sin(hx);
  double cy = cos(hy), sy = sin(hy);
  double cz = cos(hz), sz = sin(hz);
  double m00r = cy * cx, m00i = sy * sx;
  double m01r = -sy * cx, m01i = -cy * sx;
  double m10r = sy * cx, m10i = -cy * sx;
  double m11r = cy * cx, m11i = -sy * sx;
  float* o = U + t * 8;
  o[0] = (float)(cz * m00r + sz * m00i); o[1] = (float)(cz * m00i - sz * m00r);
  o[2] = (float)(cz * m01r + sz * m01i); o[3] = (float)(cz * m01i - sz * m01r);
  o[4] = (float)(cz * m10r - sz * m10i); o[5] = (float)(cz * m10i + sz * m10r);
  o[6] = (float)(cz * m11r - sz * m11i); o[7] = (float)(cz * m11i + sz * m11r);
}

// ---------------- packed gate application (N packs of 2 amps) ----------------
template <int NP>
__device__ __forceinline__ void apply_bit0(v2f RE[NP], v2f IM[NP], const float* __restrict__ u) {
  float u0 = u[0], u1 = u[1], u2 = u[2], u3 = u[3], u4 = u[4], u5 = u[5], u6 = u[6], u7 = u[7];
#pragma unroll
  for (int k = 0; k < NP; ++k) {
    float a0r = RE[k].x, a0i = IM[k].x, a1r = RE[k].y, a1i = IM[k].y;
    float n0r = u0 * a0r - u1 * a0i + u2 * a1r - u3 * a1i;
    float n0i = u0 * a0i + u1 * a0r + u2 * a1i + u3 * a1r;
    float n1r = u4 * a0r - u5 * a0i + u6 * a1r - u7 * a1i;
    float n1i = u4 * a0i + u5 * a0r + u6 * a1i + u7 * a1r;
    RE[k].x = n0r; IM[k].x = n0i; RE[k].y = n1r; IM[k].y = n1i;
  }
}

template <int NP, int PB>   // pack-bit = amp-bit - 1
__device__ __forceinline__ void apply_bitP(v2f RE[NP], v2f IM[NP], const float* __restrict__ u) {
  float u0 = u[0], u1 = u[1], u2 = u[2], u3 = u[3], u4 = u[4], u5 = u[5], u6 = u[6], u7 = u[7];
#pragma unroll
  for (int m = 0; m < NP / 2; ++m) {
    int k0 = ((m >> PB) << (PB + 1)) | (m & ((1 << PB) - 1));
    int k1 = k0 | (1 << PB);
    v2f a0r = RE[k0], a0i = IM[k0], a1r = RE[k1], a1i = IM[k1];
    v2f n0r = u0 * a0r - u1 * a0i + u2 * a1r - u3 * a1i;
    v2f n0i = u0 * a0i + u1 * a0r + u2 * a1i + u3 * a1r;
    v2f n1r = u4 * a0r - u5 * a0i + u6 * a1r - u7 * a1i;
    v2f n1i = u4 * a0i + u5 * a0r + u6 * a1i + u7 * a1r;
    RE[k0] = n0r; IM[k0] = n0i; RE[k1] = n1r; IM[k1] = n1i;
  }
}

// 4 amp-bits over 8 packs; amp-bit b uses wire (wtop - b)
__device__ __forceinline__ void apply4p(v2f RE[8], v2f IM[8], const float* __restrict__ U,
                                        int l, int wtop) {
  const float* base = U + ((l * 22 + wtop) << 3);
  apply_bit0<8>(RE, IM, base);
  apply_bitP<8, 0>(RE, IM, base - 8);
  apply_bitP<8, 1>(RE, IM, base - 16);
  apply_bitP<8, 2>(RE, IM, base - 24);
}

// 5 amp-bits over 16 packs
__device__ __forceinline__ void apply5p(v2f RE[16], v2f IM[16], const float* __restrict__ U,
                                        int l, int wtop) {
  const float* base = U + ((l * 22 + wtop) << 3);
  apply_bit0<16>(RE, IM, base);
  apply_bitP<16, 0>(RE, IM, base - 8);
  apply_bitP<16, 1>(RE, IM, base - 16);
  apply_bitP<16, 2>(RE, IM, base - 24);
  apply_bitP<16, 3>(RE, IM, base - 32);
}

// float2 (b64) LDS exchange for 16-amp state; 2 barriers.
template <typename WI, typename RI>
__device__ __forceinline__ void xchgP(float2* lds2, v2f RE[8], v2f IM[8], WI wi, RI ri) {
  __syncthreads();
#pragma unroll
  for (int d = 0; d < 16; ++d) {
    float2 a;
    if (d & 1) a = make_float2(RE[d >> 1].y, IM[d >> 1].y);
    else       a = make_float2(RE[d >> 1].x, IM[d >> 1].x);
    lds2[wi(d)] = a;
  }
  __syncthreads();
#pragma unroll
  for (int d = 0; d < 16; ++d) {
    float2 a = lds2[ri(d)];
    if (d & 1) { RE[d >> 1].y = a.x; IM[d >> 1].y = a.y; }
    else       { RE[d >> 1].x = a.x; IM[d >> 1].x = a.y; }
  }
}

// ---------------- pass A: gates on bits 0..11 (wires 21..10) ----------------
// block = 4096 contiguous amps, 256 threads x 16 amps.
// Gray-gather (layers>=1): coalesced window load + compile-time register permute:
//   G(b*16+d) = ((b^(b>>1))<<4) | ((d^(d>>1)) ^ ((b&1)<<3))
__global__ __launch_bounds__(256, 4) void k_passA(const float* __restrict__ srcRe,
                                                  const float* __restrict__ srcIm,
                                                  const float2* __restrict__ src2,
                                                  float2* __restrict__ dst,
                                                  const float* __restrict__ U,
                                                  int layer, int first) {
  __shared__ float2 lds2[4096];   // 32 KB; physical idx = j ^ (j>>4)
  const int t = threadIdx.x;
  const unsigned base = ((unsigned)blockIdx.x << 12) | ((unsigned)t << 4);
  v2f RE[8], IM[8];
  if (first) {
    const float4* r4 = (const float4*)(srcRe + base);
    const float4* i4 = (const float4*)(srcIm + base);
#pragma unroll
    for (int k = 0; k < 4; ++k) {
      float4 r = r4[k], m = i4[k];
      RE[2 * k].x     = r.x; RE[2 * k].y     = r.y;
      IM[2 * k].x     = m.x; IM[2 * k].y     = m.y;
      RE[2 * k + 1].x = r.z; RE[2 * k + 1].y = r.w;
      IM[2 * k + 1].x = m.z; IM[2 * k + 1].y = m.w;
    }
  } else {
    const unsigned b = base >> 4;
    const unsigned W = (b ^ (b >> 1)) << 4;   // aligned 16-amp window
    const float4* s4 = (const float4*)(src2 + W);
    float4 raw[8];
#pragma unroll
    for (int k = 0; k < 8; ++k) raw[k] = s4[k];
    v2f WR[8], WIm[8];
#pragma unroll
    for (int k = 0; k < 8; ++k) {
      WR[k].x = raw[k].x; WR[k].y = raw[k].z;
      WIm[k].x = raw[k].y; WIm[k].y = raw[k].w;
    }
    if (b & 1) {                               // flip bit 3 of window offset
#pragma unroll
      for (int k = 0; k < 4; ++k) {
        v2f tr = WR[k]; WR[k] = WR[k + 4]; WR[k + 4] = tr;
        v2f ti = WIm[k]; WIm[k] = WIm[k + 4]; WIm[k + 4] = ti;
      }
    }
    // v[d] = w[d ^ (d>>1)]; packed: src pack j = ((2k)^k)>>1, swap lanes if odd
#pragma unroll
    for (int k = 0; k < 8; ++k) {
      const int s = (2 * k) ^ k;
      const int j = s >> 1;
      if (s & 1) {
        RE[k].x = WR[j].y; RE[k].y = WR[j].x;
        IM[k].x = WIm[j].y; IM[k].y = WIm[j].x;
      } else {
        RE[k] = WR[j]; IM[k] = WIm[j];
      }
    }
  }
  auto wA = [&](int d) { unsigned j = ((unsigned)t << 4) | (unsigned)d; return (int)(j ^ (j >> 4)); };
  auto rB = [&](int d) { unsigned j = (((unsigned)t >> 4) << 8) | ((unsigned)d << 4) | ((unsigned)t & 15); return (int)(j ^ (j >> 4)); };
  auto rC = [&](int d) { unsigned j = ((unsigned)d << 8) | (unsigned)t; return (int)(j ^ (j >> 4)); };

  apply4p(RE, IM, U, layer, 21);      // amp bits 0..3  -> wires 21..18
  xchgP(lds2, RE, IM, wA, rB);
  apply4p(RE, IM, U, layer, 17);      // bits 4..7 -> wires 17..14
  xchgP(lds2, RE, IM, rB, rC);
  apply4p(RE, IM, U, layer, 13);      // bits 8..11 -> wires 13..10
  xchgP(lds2, RE, IM, rC, wA);
  float4* o4 = (float4*)(dst + base);
#pragma unroll
  for (int k = 0; k < 8; ++k)
    o4[k] = make_float4(RE[k].x, IM[k].x, RE[k].y, IM[k].y);
}

// ---------------- pass B: gates on bits 12..21 (wires 9..0) ----------------
// block = 1024 h-rows x 8 cols (bits 0..2), bits 3..11 = blockIdx; grid 512.
// 256 threads x 32 amps; 32 KB LDS single plane -> 2 blocks/CU for latency overlap.
// Loads batched via tmp[32] (all addresses independent -> full MLP).
// LDS swizzle e = ((h<<3)|c) ^ (((h>>5)&3)<<3):
//   writes h=u|(d<<5): bank = ((u%4)^(d&3))*8 + c -> 2-way max.
//   reads  h=d|(u<<5): bank = ((d%4)^(u&3))*8 + c -> 2-way max.
__device__ __forceinline__ int pb_idx(unsigned h, unsigned c) {
  return (int)(((h << 3) | c) ^ (((h >> 5) & 3u) << 3));
}

__global__ __launch_bounds__(256, 2) void k_passB(const float2* __restrict__ src,
                                                  float2* __restrict__ dst,
                                                  const float* __restrict__ U,
                                                  int layer) {
  __shared__ float lds[8192];   // 32 KB
  const int t = threadIdx.x;
  const unsigned c = (unsigned)(t & 7), u = (unsigned)(t >> 3);   // u in 0..31
  const unsigned lowbase = ((unsigned)blockIdx.x << 3) | c;
  const float2* sp = src + lowbase;
  float2 tmp[32];
#pragma unroll
  for (int d = 0; d < 32; ++d) {
    unsigned h = u | ((unsigned)d << 5);     // d at h-bits 5..9 (wires 4..0)
    tmp[d] = sp[(size_t)h << 12];
  }
  v2f RE[16], IM[16];
#pragma unroll
  for (int d = 0; d < 32; ++d) {
    if (d & 1) { RE[d >> 1].y = tmp[d].x; IM[d >> 1].y = tmp[d].y; }
    else       { RE[d >> 1].x = tmp[d].x; IM[d >> 1].x = tmp[d].y; }
  }
  apply5p(RE, IM, U, layer, 4);              // wires 4..0
  // exchange: d moves to h-bits 0..4 (re plane, then im plane)
  __syncthreads();
#pragma unroll
  for (int d = 0; d < 32; ++d) {
    unsigned h = u | ((unsigned)d << 5);
    lds[pb_idx(h, c)] = (d & 1) ? RE[d >> 1].y : RE[d >> 1].x;
  }
  __syncthreads();
#pragma unroll
  for (int d = 0; d < 32; ++d) {
    unsigned h = (unsigned)d | (u << 5);
    float a = lds[pb_idx(h, c)];
    if (d & 1) RE[d >> 1].y = a; else RE[d >> 1].x = a;
  }
  __syncthreads();
#pragma unroll
  for (int d = 0; d < 32; ++d) {
    unsigned h = u | ((unsigned)d << 5);
    lds[pb_idx(h, c)] = (d & 1) ? IM[d >> 1].y : IM[d >> 1].x;
  }
  __syncthreads();
#pragma unroll
  for (int d = 0; d < 32; ++d) {
    unsigned h = (unsigned)d | (u << 5);
    float a = lds[pb_idx(h, c)];
    if (d & 1) IM[d >> 1].y = a; else IM[d >> 1].x = a;
  }
  apply5p(RE, IM, U, layer, 9);              // d-bit b = global 12+b -> wires 9..5
#pragma unroll
  for (int d = 0; d < 32; ++d) {
    unsigned h = (unsigned)d | (u << 5);
    float2 a;
    if (d & 1) a = make_float2(RE[d >> 1].y, IM[d >> 1].y);
    else       a = make_float2(RE[d >> 1].x, IM[d >> 1].x);
    dst[((size_t)h << 12) | lowbase] = a;
  }
}

// ---------------- last-layer pass B fused with expvals (final-CNOT sign trick) ----------------
// Thread amp j: bits 0..11 = lowbase, 12..16 = d, 17..21 = u (u 5 bits). invGray:
//  q=0..4:  sign = parity(u >> (4-q))            -> +/-Tot
//  q=5..9:  sign = parity(d >> (9-q)) ^ pu       -> +/-W_{9-q}
//  q=10..21: sign = y_{21-q} ^ pd ^ pu           -> +/-W0, y = suffix-XOR of low
__global__ __launch_bounds__(256, 2) void k_passB_ev(const float2* __restrict__ src,
                                                     const float* __restrict__ U,
                                                     float* __restrict__ partials,
                                                     int layer) {
  __shared__ float lds[8192];
  const int t = threadIdx.x;
  const unsigned c = (unsigned)(t & 7), u = (unsigned)(t >> 3);
  const unsigned blk = blockIdx.x;
  const unsigned lowbase = (blk << 3) | c;
  const float2* sp = src + lowbase;
  float2 tmp[32];
#pragma unroll
  for (int d = 0; d < 32; ++d) {
    unsigned h = u | ((unsigned)d << 5);
    tmp[d] = sp[(size_t)h << 12];
  }
  v2f RE[16], IM[16];
#pragma unroll
  for (int d = 0; d < 32; ++d) {
    if (d & 1) { RE[d >> 1].y = tmp[d].x; IM[d >> 1].y = tmp[d].y; }
    else       { RE[d >> 1].x = tmp[d].x; IM[d >> 1].x = tmp[d].y; }
  }
  apply5p(RE, IM, U, layer, 4);
  __syncthreads();
#pragma unroll
  for (int d = 0; d < 32; ++d) {
    unsigned h = u | ((unsigned)d << 5);
    lds[pb_idx(h, c)] = (d & 1) ? RE[d >> 1].y : RE[d >> 1].x;
  }
  __syncthreads();
#pragma unroll
  for (int d = 0; d < 32; ++d) {
    unsigned h = (unsigned)d | (u << 5);
    float a = lds[pb_idx(h, c)];
    if (d & 1) RE[d >> 1].y = a; else RE[d >> 1].x = a;
  }
  __syncthreads();
#pragma unroll
  for (int d = 0; d < 32; ++d) {
    unsigned h = u | ((unsigned)d << 5);
    lds[pb_idx(h, c)] = (d & 1) ? IM[d >> 1].y : IM[d >> 1].x;
  }
  __syncthreads();
#pragma unroll
  for (int d = 0; d < 32; ++d) {
    unsigned h = (unsigned)d | (u << 5);
    float a = lds[pb_idx(h, c)];
    if (d & 1) IM[d >> 1].y = a; else IM[d >> 1].x = a;
  }
  apply5p(RE, IM, U, layer, 9);

  // ---- fused expval epilogue: suffix-parity Walsh fold over 5 d-bits ----
  v2f PS[16];
#pragma unroll
  for (int k = 0; k < 16; ++k) PS[k] = RE[k] * RE[k] + IM[k] * IM[k];
  v2f S4[8], B4[8];
#pragma unroll
  for (int k = 0; k < 8; ++k) { S4[k] = PS[k] + PS[k + 8]; B4[k] = PS[k] - PS[k + 8]; }
  float Tot = 0.f, W4 = 0.f;
#pragma unroll
  for (int k = 0; k < 8; ++k) { Tot += S4[k].x + S4[k].y; W4 += B4[k].x + B4[k].y; }
  v2f B3[4];
#pragma unroll
  for (int k = 0; k < 4; ++k) B3[k] = B4[k] - B4[k + 4];
  float W3 = (B3[0].x + B3[0].y) + (B3[1].x + B3[1].y) + (B3[2].x + B3[2].y) + (B3[3].x + B3[3].y);
  v2f B2[2];
  B2[0] = B3[0] - B3[2]; B2[1] = B3[1] - B3[3];
  float W2 = (B2[0].x + B2[0].y) + (B2[1].x + B2[1].y);
  v2f B1 = B2[0] - B2[1];
  float W1 = B1.x + B1.y;
  float W0 = B1.x - B1.y;

  unsigned y = lowbase; y ^= y >> 1; y ^= y >> 2; y ^= y >> 4; y ^= y >> 8;  // suffix-XOR
  unsigned pu = (unsigned)__popc(u) & 1u;
  float acc[22];
#pragma unroll
  for (int q = 0; q <= 4; ++q)
    acc[q] = ((unsigned)__popc(u >> (4 - q)) & 1u) ? -Tot : Tot;
  {
    float W[5] = {W0, W1, W2, W3, W4};
#pragma unroll
    for (int q = 5; q <= 9; ++q)
      acc[q] = pu ? -W[9 - q] : W[9 - q];
  }
#pragma unroll
  for (int q = 10; q <= 21; ++q)
    acc[q] = (((y >> (21 - q)) ^ pu) & 1u) ? -W0 : W0;

  __syncthreads();
  float* red = lds;                          // 4 waves * 23
  const int lane = t & 63, wv = t >> 6;
#pragma unroll
  for (int q = 0; q < 22; ++q) {
    float s = acc[q];
    for (int off = 32; off > 0; off >>= 1) s += __shfl_down(s, off, 64);
    if (lane == 0) red[wv * 23 + q] = s;
  }
  {
    float s = Tot;
    for (int off = 32; off > 0; off >>= 1) s += __shfl_down(s, off, 64);
    if (lane == 0) red[wv * 23 + 22] = s;
  }
  __syncthreads();
  if (t < 23) {
    float s = 0.f;
#pragma unroll
    for (int w = 0; w < 4; ++w) s += red[w * 23 + t];
    partials[t * 512 + blk] = s;
  }
}

__global__ void k_final(const float* __restrict__ partials, float* __restrict__ out) {
  __shared__ double res[32];
  const int t = threadIdx.x;
  const int r = t >> 3, l8 = t & 7;
  if (r < 23) {
    double s = 0.0;
    const float* p = partials + r * 512 + l8 * 64;
    for (int k = 0; k < 64; ++k) s += (double)p[k];
    for (int off = 4; off > 0; off >>= 1) s += __shfl_down(s, off, 8);
    if (l8 == 0) res[r] = s;
  }
  __syncthreads();
  if (t < 22) out[t] = (float)(res[t] / res[22]);  // normalization folded in
}

extern "C" void kernel_launch(void* const* d_in, const int* in_sizes, int n_in,
                              void* d_out, int out_size, void* d_ws, size_t ws_size,
                              hipStream_t stream) {
  const float* params = (const float*)d_in[0];   // [4][22][3]
  const float* sre = (const float*)d_in[1];      // [DIM]
  const float* sim = (const float*)d_in[2];      // [DIM]
  float* out = (float*)d_out;                    // [22]
  char* ws = (char*)d_ws;
  float* U = (float*)ws;                         // 88 * 8 floats
  float* partials = (float*)(ws + 4096);         // 23 * 512 floats
  float2* buf0 = (float2*)(ws + 131072);         // 32 MB
  float2* buf1 = buf0 + DIM;                     // 32 MB

  k_gates<<<1, 128, 0, stream>>>(params, U);
  // layer 0 (no permutation on input)
  k_passA<<<1024, 256, 0, stream>>>(sre, sim, nullptr, buf0, U, 0, 1);
  k_passB<<<512, 256, 0, stream>>>(buf0, buf1, U, 0);
  for (int l = 1; l < 3; ++l) {
    k_passA<<<1024, 256, 0, stream>>>(nullptr, nullptr, buf1, buf0, U, l, 0);
    k_passB<<<512, 256, 0, stream>>>(buf0, buf1, U, l);
  }
  k_passA<<<1024, 256, 0, stream>>>(nullptr, nullptr, buf1, buf0, U, 3, 0);
  k_passB_ev<<<512, 256, 0, stream>>>(buf0, U, partials, 3);
  k_final<<<1, 256, 0, stream>>>(partials, out);
}

// Round 8
// 231.362 us; speedup vs baseline: 1.0470x; 1.0470x over previous
//
#include <hip/hip_runtime.h>
#include <math.h>

#define NQ 22
#define DIM (1u << NQ)

typedef float v2f __attribute__((ext_vector_type(2)));

// Intermediate-buffer layout (blocked transpose):
//   amp j: low = j&15, mid = (j>>4)&255, h = j>>12
//   storage S(j) = mid<<14 | h<<4 | low
// -> pass B (fixed mid) owns a contiguous 128 KB chunk; pass A (fixed h) reads/writes
//    per-thread-contiguous 128 B segments at 128 KB stride (the proven-fast pattern).

// ---------------- fused gate matrices: U = RZ * RY * RX, fp64 -> fp32 ----------------
__global__ void k_gates(const float* __restrict__ params, float* __restrict__ U) {
  int t = blockIdx.x * blockDim.x + threadIdx.x;
  if (t >= 88) return;               // t = l*22 + q
  const float* p = params + t * 3;
  double hx = 0.5 * (double)p[0], hy = 0.5 * (double)p[1], hz = 0.5 * (double)p[2];
  double cx = cos(hx), sx = sin(hx);
  double cy = cos(hy), sy = sin(hy);
  double cz = cos(hz), sz = sin(hz);
  double m00r = cy * cx, m00i = sy * sx;
  double m01r = -sy * cx, m01i = -cy * sx;
  double m10r = sy * cx, m10i = -cy * sx;
  double m11r = cy * cx, m11i = -sy * sx;
  float* o = U + t * 8;
  o[0] = (float)(cz * m00r + sz * m00i); o[1] = (float)(cz * m00i - sz * m00r);
  o[2] = (float)(cz * m01r + sz * m01i); o[3] = (float)(cz * m01i - sz * m01r);
  o[4] = (float)(cz * m10r - sz * m10i); o[5] = (float)(cz * m10i + sz * m10r);
  o[6] = (float)(cz * m11r - sz * m11i); o[7] = (float)(cz * m11i + sz * m11r);
}

// ---------------- packed gate application (N packs of 2 amps) ----------------
template <int NP>
__device__ __forceinline__ void apply_bit0(v2f RE[NP], v2f IM[NP], const float* __restrict__ u) {
  float u0 = u[0], u1 = u[1], u2 = u[2], u3 = u[3], u4 = u[4], u5 = u[5], u6 = u[6], u7 = u[7];
#pragma unroll
  for (int k = 0; k < NP; ++k) {
    float a0r = RE[k].x, a0i = IM[k].x, a1r = RE[k].y, a1i = IM[k].y;
    float n0r = u0 * a0r - u1 * a0i + u2 * a1r - u3 * a1i;
    float n0i = u0 * a0i + u1 * a0r + u2 * a1i + u3 * a1r;
    float n1r = u4 * a0r - u5 * a0i + u6 * a1r - u7 * a1i;
    float n1i = u4 * a0i + u5 * a0r + u6 * a1i + u7 * a1r;
    RE[k].x = n0r; IM[k].x = n0i; RE[k].y = n1r; IM[k].y = n1i;
  }
}

template <int NP, int PB>   // pack-bit = amp-bit - 1
__device__ __forceinline__ void apply_bitP(v2f RE[NP], v2f IM[NP], const float* __restrict__ u) {
  float u0 = u[0], u1 = u[1], u2 = u[2], u3 = u[3], u4 = u[4], u5 = u[5], u6 = u[6], u7 = u[7];
#pragma unroll
  for (int m = 0; m < NP / 2; ++m) {
    int k0 = ((m >> PB) << (PB + 1)) | (m & ((1 << PB) - 1));
    int k1 = k0 | (1 << PB);
    v2f a0r = RE[k0], a0i = IM[k0], a1r = RE[k1], a1i = IM[k1];
    v2f n0r = u0 * a0r - u1 * a0i + u2 * a1r - u3 * a1i;
    v2f n0i = u0 * a0i + u1 * a0r + u2 * a1i + u3 * a1r;
    v2f n1r = u4 * a0r - u5 * a0i + u6 * a1r - u7 * a1i;
    v2f n1i = u4 * a0i + u5 * a0r + u6 * a1i + u7 * a1r;
    RE[k0] = n0r; IM[k0] = n0i; RE[k1] = n1r; IM[k1] = n1i;
  }
}

// 4 amp-bits over 8 packs; amp-bit b uses wire (wtop - b)
__device__ __forceinline__ void apply4p(v2f RE[8], v2f IM[8], const float* __restrict__ U,
                                        int l, int wtop) {
  const float* base = U + ((l * 22 + wtop) << 3);
  apply_bit0<8>(RE, IM, base);
  apply_bitP<8, 0>(RE, IM, base - 8);
  apply_bitP<8, 1>(RE, IM, base - 16);
  apply_bitP<8, 2>(RE, IM, base - 24);
}

// 5 amp-bits over 16 packs
__device__ __forceinline__ void apply5p(v2f RE[16], v2f IM[16], const float* __restrict__ U,
                                        int l, int wtop) {
  const float* base = U + ((l * 22 + wtop) << 3);
  apply_bit0<16>(RE, IM, base);
  apply_bitP<16, 0>(RE, IM, base - 8);
  apply_bitP<16, 1>(RE, IM, base - 16);
  apply_bitP<16, 2>(RE, IM, base - 24);
  apply_bitP<16, 3>(RE, IM, base - 32);
}

// float2 (b64) LDS exchange for 16-amp state; 2 barriers.
template <typename WI, typename RI>
__device__ __forceinline__ void xchgP(float2* lds2, v2f RE[8], v2f IM[8], WI wi, RI ri) {
  __syncthreads();
#pragma unroll
  for (int d = 0; d < 16; ++d) {
    float2 a;
    if (d & 1) a = make_float2(RE[d >> 1].y, IM[d >> 1].y);
    else       a = make_float2(RE[d >> 1].x, IM[d >> 1].x);
    lds2[wi(d)] = a;
  }
  __syncthreads();
#pragma unroll
  for (int d = 0; d < 16; ++d) {
    float2 a = lds2[ri(d)];
    if (d & 1) { RE[d >> 1].y = a.x; IM[d >> 1].y = a.y; }
    else       { RE[d >> 1].x = a.x; IM[d >> 1].x = a.y; }
  }
}

// ---------------- pass A: gates on amp bits 0..11 (wires 21..10) ----------------
// block = fixed h (grid 1024), 256 threads x 16 amps; in-block amp idx = t<<4 | low.
// Gray-gather (layers>=1): window w = b^(b>>1), b = h<<8 | t; window is one
// contiguous 128 B segment at S = (w&255)<<14 | (w>>8)<<4.
__global__ __launch_bounds__(256, 4) void k_passA(const float* __restrict__ srcRe,
                                                  const float* __restrict__ srcIm,
                                                  const float2* __restrict__ src2,
                                                  float2* __restrict__ dst,
                                                  const float* __restrict__ U,
                                                  int layer, int first) {
  __shared__ float2 lds2[4096];   // 32 KB; physical idx = j ^ (j>>4)
  const int t = threadIdx.x;
  const unsigned H = blockIdx.x;
  v2f RE[8], IM[8];
  if (first) {
    const unsigned jbase = (H << 12) | ((unsigned)t << 4);   // natural order input
    const float4* r4 = (const float4*)(srcRe + jbase);
    const float4* i4 = (const float4*)(srcIm + jbase);
#pragma unroll
    for (int k = 0; k < 4; ++k) {
      float4 r = r4[k], m = i4[k];
      RE[2 * k].x     = r.x; RE[2 * k].y     = r.y;
      IM[2 * k].x     = m.x; IM[2 * k].y     = m.y;
      RE[2 * k + 1].x = r.z; RE[2 * k + 1].y = r.w;
      IM[2 * k + 1].x = m.z; IM[2 * k + 1].y = m.w;
    }
  } else {
    const unsigned b = (H << 8) | (unsigned)t;
    const unsigned w = b ^ (b >> 1);
    const float4* s4 = (const float4*)(src2 + (((size_t)(w & 255u) << 14) | ((size_t)(w >> 8) << 4)));
    float4 raw[8];
#pragma unroll
    for (int k = 0; k < 8; ++k) raw[k] = s4[k];
    v2f WR[8], WIm[8];
#pragma unroll
    for (int k = 0; k < 8; ++k) {
      WR[k].x = raw[k].x; WR[k].y = raw[k].z;
      WIm[k].x = raw[k].y; WIm[k].y = raw[k].w;
    }
    if (b & 1) {                               // flip bit 3 of window offset
#pragma unroll
      for (int k = 0; k < 4; ++k) {
        v2f tr = WR[k]; WR[k] = WR[k + 4]; WR[k + 4] = tr;
        v2f ti = WIm[k]; WIm[k] = WIm[k + 4]; WIm[k + 4] = ti;
      }
    }
    // v[d] = w[d ^ (d>>1)]; packed: src pack j = ((2k)^k)>>1, swap lanes if odd
#pragma unroll
    for (int k = 0; k < 8; ++k) {
      const int s = (2 * k) ^ k;
      const int j = s >> 1;
      if (s & 1) {
        RE[k].x = WR[j].y; RE[k].y = WR[j].x;
        IM[k].x = WIm[j].y; IM[k].y = WIm[j].x;
      } else {
        RE[k] = WR[j]; IM[k] = WIm[j];
      }
    }
  }
  auto wA = [&](int d) { unsigned j = ((unsigned)t << 4) | (unsigned)d; return (int)(j ^ (j >> 4)); };
  auto rB = [&](int d) { unsigned j = (((unsigned)t >> 4) << 8) | ((unsigned)d << 4) | ((unsigned)t & 15); return (int)(j ^ (j >> 4)); };
  auto rC = [&](int d) { unsigned j = ((unsigned)d << 8) | (unsigned)t; return (int)(j ^ (j >> 4)); };

  apply4p(RE, IM, U, layer, 21);      // amp bits 0..3  -> wires 21..18
  xchgP(lds2, RE, IM, wA, rB);
  apply4p(RE, IM, U, layer, 17);      // bits 4..7 -> wires 17..14
  xchgP(lds2, RE, IM, rB, rC);
  apply4p(RE, IM, U, layer, 13);      // bits 8..11 -> wires 13..10
  xchgP(lds2, RE, IM, rC, wA);
  // store to blocked-transpose layout: S = t<<14 | H<<4 | low (contiguous 128 B)
  float4* o4 = (float4*)(dst + (((size_t)t << 14) | ((size_t)H << 4)));
#pragma unroll
  for (int k = 0; k < 8; ++k)
    o4[k] = make_float4(RE[k].x, IM[k].x, RE[k].y, IM[k].y);
}

// ---------------- pass B: gates on amp bits 12..21 (wires 9..0) ----------------
// block = fixed mid (grid 256): one contiguous 128 KB chunk. 512 threads x 32 amps.
// Round 1: thread (c = t&15, u = t>>4 = h-bits 0..4), d = h-bits 5..9 -> wires 4..0.
// Exchange d<->u, round 2 -> wires 9..5. Loads: 512 B contiguous per wave instr.
// LDS swizzle e = (h<<4|c) ^ (((h>>5)&1)<<4): 2-way max both directions.
__device__ __forceinline__ int pb_idx(unsigned h, unsigned c) {
  return (int)(((h << 4) | c) ^ (((h >> 5) & 1u) << 4));
}

__global__ __launch_bounds__(512, 2) void k_passB(const float2* __restrict__ src,
                                                  float2* __restrict__ dst,
                                                  const float* __restrict__ U,
                                                  int layer) {
  __shared__ float lds[16384];   // 64 KB
  const int t = threadIdx.x;
  const unsigned c = (unsigned)(t & 15), u = (unsigned)(t >> 4);   // u in 0..31
  const float2* sp = src + (((size_t)blockIdx.x << 14) | c);
  float2 tmp[32];
#pragma unroll
  for (int d = 0; d < 32; ++d) {
    unsigned h = u | ((unsigned)d << 5);
    tmp[d] = sp[(size_t)h << 4];
  }
  v2f RE[16], IM[16];
#pragma unroll
  for (int d = 0; d < 32; ++d) {
    if (d & 1) { RE[d >> 1].y = tmp[d].x; IM[d >> 1].y = tmp[d].y; }
    else       { RE[d >> 1].x = tmp[d].x; IM[d >> 1].x = tmp[d].y; }
  }
  apply5p(RE, IM, U, layer, 4);              // wires 4..0
  __syncthreads();
#pragma unroll
  for (int d = 0; d < 32; ++d) {
    unsigned h = u | ((unsigned)d << 5);
    lds[pb_idx(h, c)] = (d & 1) ? RE[d >> 1].y : RE[d >> 1].x;
  }
  __syncthreads();
#pragma unroll
  for (int d = 0; d < 32; ++d) {
    unsigned h = (unsigned)d | (u << 5);
    float a = lds[pb_idx(h, c)];
    if (d & 1) RE[d >> 1].y = a; else RE[d >> 1].x = a;
  }
  __syncthreads();
#pragma unroll
  for (int d = 0; d < 32; ++d) {
    unsigned h = u | ((unsigned)d << 5);
    lds[pb_idx(h, c)] = (d & 1) ? IM[d >> 1].y : IM[d >> 1].x;
  }
  __syncthreads();
#pragma unroll
  for (int d = 0; d < 32; ++d) {
    unsigned h = (unsigned)d | (u << 5);
    float a = lds[pb_idx(h, c)];
    if (d & 1) IM[d >> 1].y = a; else IM[d >> 1].x = a;
  }
  apply5p(RE, IM, U, layer, 9);              // wires 9..5
  float2* dp = dst + (((size_t)blockIdx.x << 14) | c);
#pragma unroll
  for (int d = 0; d < 32; ++d) {
    unsigned h = (unsigned)d | (u << 5);
    float2 a;
    if (d & 1) a = make_float2(RE[d >> 1].y, IM[d >> 1].y);
    else       a = make_float2(RE[d >> 1].x, IM[d >> 1].x);
    dp[(size_t)h << 4] = a;
  }
}

// ---------------- last-layer pass B fused with expvals (final-CNOT sign trick) ----------------
// Thread amp j: bits 0..3 = c, 4..11 = blk, 12..16 = d, 17..21 = u. invGray:
//  q=0..4:  sign = parity(u >> (4-q))         -> +/-Tot
//  q=5..9:  sign = parity(d >> (9-q)) ^ pu    -> +/-W_{9-q}
//  q=10..21: sign = y_{21-q} ^ pd ^ pu        -> +/-W0, y = suffix-XOR of (blk<<4|c)
__global__ __launch_bounds__(512, 2) void k_passB_ev(const float2* __restrict__ src,
                                                     const float* __restrict__ U,
                                                     float* __restrict__ partials,
                                                     int layer) {
  __shared__ float lds[16384];
  const int t = threadIdx.x;
  const unsigned c = (unsigned)(t & 15), u = (unsigned)(t >> 4);
  const unsigned blk = blockIdx.x;
  const float2* sp = src + (((size_t)blk << 14) | c);
  float2 tmp[32];
#pragma unroll
  for (int d = 0; d < 32; ++d) {
    unsigned h = u | ((unsigned)d << 5);
    tmp[d] = sp[(size_t)h << 4];
  }
  v2f RE[16], IM[16];
#pragma unroll
  for (int d = 0; d < 32; ++d) {
    if (d & 1) { RE[d >> 1].y = tmp[d].x; IM[d >> 1].y = tmp[d].y; }
    else       { RE[d >> 1].x = tmp[d].x; IM[d >> 1].x = tmp[d].y; }
  }
  apply5p(RE, IM, U, layer, 4);
  __syncthreads();
#pragma unroll
  for (int d = 0; d < 32; ++d) {
    unsigned h = u | ((unsigned)d << 5);
    lds[pb_idx(h, c)] = (d & 1) ? RE[d >> 1].y : RE[d >> 1].x;
  }
  __syncthreads();
#pragma unroll
  for (int d = 0; d < 32; ++d) {
    unsigned h = (unsigned)d | (u << 5);
    float a = lds[pb_idx(h, c)];
    if (d & 1) RE[d >> 1].y = a; else RE[d >> 1].x = a;
  }
  __syncthreads();
#pragma unroll
  for (int d = 0; d < 32; ++d) {
    unsigned h = u | ((unsigned)d << 5);
    lds[pb_idx(h, c)] = (d & 1) ? IM[d >> 1].y : IM[d >> 1].x;
  }
  __syncthreads();
#pragma unroll
  for (int d = 0; d < 32; ++d) {
    unsigned h = (unsigned)d | (u << 5);
    float a = lds[pb_idx(h, c)];
    if (d & 1) IM[d >> 1].y = a; else IM[d >> 1].x = a;
  }
  apply5p(RE, IM, U, layer, 9);

  // ---- fused expval epilogue: suffix-parity Walsh fold over 5 d-bits ----
  v2f PS[16];
#pragma unroll
  for (int k = 0; k < 16; ++k) PS[k] = RE[k] * RE[k] + IM[k] * IM[k];
  v2f S4[8], B4[8];
#pragma unroll
  for (int k = 0; k < 8; ++k) { S4[k] = PS[k] + PS[k + 8]; B4[k] = PS[k] - PS[k + 8]; }
  float Tot = 0.f, W4 = 0.f;
#pragma unroll
  for (int k = 0; k < 8; ++k) { Tot += S4[k].x + S4[k].y; W4 += B4[k].x + B4[k].y; }
  v2f B3[4];
#pragma unroll
  for (int k = 0; k < 4; ++k) B3[k] = B4[k] - B4[k + 4];
  float W3 = (B3[0].x + B3[0].y) + (B3[1].x + B3[1].y) + (B3[2].x + B3[2].y) + (B3[3].x + B3[3].y);
  v2f B2[2];
  B2[0] = B3[0] - B3[2]; B2[1] = B3[1] - B3[3];
  float W2 = (B2[0].x + B2[0].y) + (B2[1].x + B2[1].y);
  v2f B1 = B2[0] - B2[1];
  float W1 = B1.x + B1.y;
  float W0 = B1.x - B1.y;

  unsigned lowfull = (blk << 4) | c;
  unsigned y = lowfull; y ^= y >> 1; y ^= y >> 2; y ^= y >> 4; y ^= y >> 8;  // suffix-XOR
  unsigned pu = (unsigned)__popc(u) & 1u;
  float acc[22];
#pragma unroll
  for (int q = 0; q <= 4; ++q)
    acc[q] = ((unsigned)__popc(u >> (4 - q)) & 1u) ? -Tot : Tot;
  {
    float W[5] = {W0, W1, W2, W3, W4};
#pragma unroll
    for (int q = 5; q <= 9; ++q)
      acc[q] = pu ? -W[9 - q] : W[9 - q];
  }
#pragma unroll
  for (int q = 10; q <= 21; ++q)
    acc[q] = (((y >> (21 - q)) ^ pu) & 1u) ? -W0 : W0;

  __syncthreads();
  float* red = lds;                          // 8 waves * 23
  const int lane = t & 63, wv = t >> 6;
#pragma unroll
  for (int q = 0; q < 22; ++q) {
    float s = acc[q];
    for (int off = 32; off > 0; off >>= 1) s += __shfl_down(s, off, 64);
    if (lane == 0) red[wv * 23 + q] = s;
  }
  {
    float s = Tot;
    for (int off = 32; off > 0; off >>= 1) s += __shfl_down(s, off, 64);
    if (lane == 0) red[wv * 23 + 22] = s;
  }
  __syncthreads();
  if (t < 23) {
    float s = 0.f;
#pragma unroll
    for (int w = 0; w < 8; ++w) s += red[w * 23 + t];
    partials[t * 256 + blk] = s;
  }
}

__global__ void k_final(const float* __restrict__ partials, float* __restrict__ out) {
  __shared__ double res[32];
  const int t = threadIdx.x;
  const int r = t >> 3, l8 = t & 7;
  if (r < 23) {
    double s = 0.0;
    const float* p = partials + r * 256 + l8 * 32;
    for (int k = 0; k < 32; ++k) s += (double)p[k];
    for (int off = 4; off > 0; off >>= 1) s += __shfl_down(s, off, 8);
    if (l8 == 0) res[r] = s;
  }
  __syncthreads();
  if (t < 22) out[t] = (float)(res[t] / res[22]);  // normalization folded in
}

extern "C" void kernel_launch(void* const* d_in, const int* in_sizes, int n_in,
                              void* d_out, int out_size, void* d_ws, size_t ws_size,
                              hipStream_t stream) {
  const float* params = (const float*)d_in[0];   // [4][22][3]
  const float* sre = (const float*)d_in[1];      // [DIM]
  const float* sim = (const float*)d_in[2];      // [DIM]
  float* out = (float*)d_out;                    // [22]
  char* ws = (char*)d_ws;
  float* U = (float*)ws;                         // 88 * 8 floats
  float* partials = (float*)(ws + 4096);         // 23 * 256 floats
  float2* buf0 = (float2*)(ws + 131072);         // 32 MB
  float2* buf1 = buf0 + DIM;                     // 32 MB

  k_gates<<<1, 128, 0, stream>>>(params, U);
  // layer 0 (no permutation on input)
  k_passA<<<1024, 256, 0, stream>>>(sre, sim, nullptr, buf0, U, 0, 1);
  k_passB<<<256, 512, 0, stream>>>(buf0, buf1, U, 0);
  for (int l = 1; l < 3; ++l) {
    k_passA<<<1024, 256, 0, stream>>>(nullptr, nullptr, buf1, buf0, U, l, 0);
    k_passB<<<256, 512, 0, stream>>>(buf0, buf1, U, l);
  }
  k_passA<<<1024, 256, 0, stream>>>(nullptr, nullptr, buf1, buf0, U, 3, 0);
  k_passB_ev<<<256, 512, 0, stream>>>(buf0, U, partials, 3);
  k_final<<<1, 256, 0, stream>>>(partials, out);
}

// Round 9
// 219.264 us; speedup vs baseline: 1.1048x; 1.0552x over previous
//
#include <hip/hip_runtime.h>
#include <math.h>

#define NQ 22
#define DIM (1u << NQ)

typedef float v2f __attribute__((ext_vector_type(2)));

// Layout scheme (transposes on STORE side only):
//   natural index j: low = j&7, mid = (j>>3)&511, h = j>>12
//   blocked S(j) = mid<<13 | h<<3 | low
// A reads natural (tile-contiguous, incl. Gray-permuted tile), stores blocked.
// B reads blocked (contiguous 64 KB chunk), stores natural.

// ---------------- fused gate matrices: U = RZ * RY * RX, fp64 -> fp32 ----------------
__global__ void k_gates(const float* __restrict__ params, float* __restrict__ U) {
  int t = blockIdx.x * blockDim.x + threadIdx.x;
  if (t >= 88) return;               // t = l*22 + q
  const float* p = params + t * 3;
  double hx = 0.5 * (double)p[0], hy = 0.5 * (double)p[1], hz = 0.5 * (double)p[2];
  double cx = cos(hx), sx = sin(hx);
  double cy = cos(hy), sy = sin(hy);
  double cz = cos(hz), sz = sin(hz);
  double m00r = cy * cx, m00i = sy * sx;
  double m01r = -sy * cx, m01i = -cy * sx;
  double m10r = sy * cx, m10i = -cy * sx;
  double m11r = cy * cx, m11i = -sy * sx;
  float* o = U + t * 8;
  o[0] = (float)(cz * m00r + sz * m00i); o[1] = (float)(cz * m00i - sz * m00r);
  o[2] = (float)(cz * m01r + sz * m01i); o[3] = (float)(cz * m01i - sz * m01r);
  o[4] = (float)(cz * m10r - sz * m10i); o[5] = (float)(cz * m10i + sz * m10r);
  o[6] = (float)(cz * m11r - sz * m11i); o[7] = (float)(cz * m11i + sz * m11r);
}

// ---------------- packed gate application (N packs of 2 amps) ----------------
template <int NP>
__device__ __forceinline__ void apply_bit0(v2f RE[NP], v2f IM[NP], const float* __restrict__ u) {
  float u0 = u[0], u1 = u[1], u2 = u[2], u3 = u[3], u4 = u[4], u5 = u[5], u6 = u[6], u7 = u[7];
#pragma unroll
  for (int k = 0; k < NP; ++k) {
    float a0r = RE[k].x, a0i = IM[k].x, a1r = RE[k].y, a1i = IM[k].y;
    float n0r = u0 * a0r - u1 * a0i + u2 * a1r - u3 * a1i;
    float n0i = u0 * a0i + u1 * a0r + u2 * a1i + u3 * a1r;
    float n1r = u4 * a0r - u5 * a0i + u6 * a1r - u7 * a1i;
    float n1i = u4 * a0i + u5 * a0r + u6 * a1i + u7 * a1r;
    RE[k].x = n0r; IM[k].x = n0i; RE[k].y = n1r; IM[k].y = n1i;
  }
}

template <int NP, int PB>   // pack-bit = amp-bit - 1
__device__ __forceinline__ void apply_bitP(v2f RE[NP], v2f IM[NP], const float* __restrict__ u) {
  float u0 = u[0], u1 = u[1], u2 = u[2], u3 = u[3], u4 = u[4], u5 = u[5], u6 = u[6], u7 = u[7];
#pragma unroll
  for (int m = 0; m < NP / 2; ++m) {
    int k0 = ((m >> PB) << (PB + 1)) | (m & ((1 << PB) - 1));
    int k1 = k0 | (1 << PB);
    v2f a0r = RE[k0], a0i = IM[k0], a1r = RE[k1], a1i = IM[k1];
    v2f n0r = u0 * a0r - u1 * a0i + u2 * a1r - u3 * a1i;
    v2f n0i = u0 * a0i + u1 * a0r + u2 * a1i + u3 * a1r;
    v2f n1r = u4 * a0r - u5 * a0i + u6 * a1r - u7 * a1i;
    v2f n1i = u4 * a0i + u5 * a0r + u6 * a1i + u7 * a1r;
    RE[k0] = n0r; IM[k0] = n0i; RE[k1] = n1r; IM[k1] = n1i;
  }
}

__device__ __forceinline__ void apply4p(v2f RE[8], v2f IM[8], const float* __restrict__ U,
                                        int l, int wtop) {
  const float* base = U + ((l * 22 + wtop) << 3);
  apply_bit0<8>(RE, IM, base);
  apply_bitP<8, 0>(RE, IM, base - 8);
  apply_bitP<8, 1>(RE, IM, base - 16);
  apply_bitP<8, 2>(RE, IM, base - 24);
}

__device__ __forceinline__ void apply5p(v2f RE[16], v2f IM[16], const float* __restrict__ U,
                                        int l, int wtop) {
  const float* base = U + ((l * 22 + wtop) << 3);
  apply_bit0<16>(RE, IM, base);
  apply_bitP<16, 0>(RE, IM, base - 8);
  apply_bitP<16, 1>(RE, IM, base - 16);
  apply_bitP<16, 2>(RE, IM, base - 24);
  apply_bitP<16, 3>(RE, IM, base - 32);
}

// float2 (b64) LDS exchange for 16-amp state; 2 barriers.
template <typename WI, typename RI>
__device__ __forceinline__ void xchgP(float2* lds2, v2f RE[8], v2f IM[8], WI wi, RI ri) {
  __syncthreads();
#pragma unroll
  for (int d = 0; d < 16; ++d) {
    float2 a;
    if (d & 1) a = make_float2(RE[d >> 1].y, IM[d >> 1].y);
    else       a = make_float2(RE[d >> 1].x, IM[d >> 1].x);
    lds2[wi(d)] = a;
  }
  __syncthreads();
#pragma unroll
  for (int d = 0; d < 16; ++d) {
    float2 a = lds2[ri(d)];
    if (d & 1) { RE[d >> 1].y = a.x; IM[d >> 1].y = a.y; }
    else       { RE[d >> 1].x = a.x; IM[d >> 1].x = a.y; }
  }
}

// ---------------- pass A: gates on amp bits 0..11 (wires 21..10) ----------------
// block = tile H (grid 1024), 256 threads x 16 amps.
// Read NATURAL: layer 0 from inputs; layers>=1 tile W=H^(H>>1) (contiguous 32 KB,
// lane-permuted windows + in-register Gray permute). Only 2 LDS exchanges; store
// directly from rC arrangement to BLOCKED layout (full 64 B segments).
__global__ __launch_bounds__(256, 4) void k_passA(const float* __restrict__ srcRe,
                                                  const float* __restrict__ srcIm,
                                                  const float2* __restrict__ src2,
                                                  float2* __restrict__ dst,
                                                  const float* __restrict__ U,
                                                  int layer, int first) {
  __shared__ float2 lds2[4096];   // 32 KB; physical idx = j ^ (j>>4)
  const int t = threadIdx.x;
  const unsigned H = blockIdx.x;
  v2f RE[8], IM[8];
  if (first) {
    const unsigned jbase = (H << 12) | ((unsigned)t << 4);
    const float4* r4 = (const float4*)(srcRe + jbase);
    const float4* i4 = (const float4*)(srcIm + jbase);
#pragma unroll
    for (int k = 0; k < 4; ++k) {
      float4 r = r4[k], m = i4[k];
      RE[2 * k].x     = r.x; RE[2 * k].y     = r.y;
      IM[2 * k].x     = m.x; IM[2 * k].y     = m.y;
      RE[2 * k + 1].x = r.z; RE[2 * k + 1].y = r.w;
      IM[2 * k + 1].x = m.z; IM[2 * k + 1].y = m.w;
    }
  } else {
    const unsigned b = (H << 8) | (unsigned)t;
    const unsigned w = b ^ (b >> 1);               // 16-amp window, tile-contiguous
    const float4* s4 = (const float4*)(src2 + ((size_t)w << 4));
    float4 raw[8];
#pragma unroll
    for (int k = 0; k < 8; ++k) raw[k] = s4[k];
    v2f WR[8], WIm[8];
#pragma unroll
    for (int k = 0; k < 8; ++k) {
      WR[k].x = raw[k].x; WR[k].y = raw[k].z;
      WIm[k].x = raw[k].y; WIm[k].y = raw[k].w;
    }
    if (b & 1) {                               // flip bit 3 of window offset
#pragma unroll
      for (int k = 0; k < 4; ++k) {
        v2f tr = WR[k]; WR[k] = WR[k + 4]; WR[k + 4] = tr;
        v2f ti = WIm[k]; WIm[k] = WIm[k + 4]; WIm[k + 4] = ti;
      }
    }
    // v[d] = w[d ^ (d>>1)]; packed: src pack j = ((2k)^k)>>1, swap lanes if odd
#pragma unroll
    for (int k = 0; k < 8; ++k) {
      const int s = (2 * k) ^ k;
      const int j = s >> 1;
      if (s & 1) {
        RE[k].x = WR[j].y; RE[k].y = WR[j].x;
        IM[k].x = WIm[j].y; IM[k].y = WIm[j].x;
      } else {
        RE[k] = WR[j]; IM[k] = WIm[j];
      }
    }
  }
  auto wA = [&](int d) { unsigned j = ((unsigned)t << 4) | (unsigned)d; return (int)(j ^ (j >> 4)); };
  auto rB = [&](int d) { unsigned j = (((unsigned)t >> 4) << 8) | ((unsigned)d << 4) | ((unsigned)t & 15); return (int)(j ^ (j >> 4)); };
  auto rC = [&](int d) { unsigned j = ((unsigned)d << 8) | (unsigned)t; return (int)(j ^ (j >> 4)); };

  apply4p(RE, IM, U, layer, 21);      // amp bits 0..3  -> wires 21..18
  xchgP(lds2, RE, IM, wA, rB);
  apply4p(RE, IM, U, layer, 17);      // bits 4..7 -> wires 17..14
  xchgP(lds2, RE, IM, rB, rC);
  apply4p(RE, IM, U, layer, 13);      // bits 8..11 -> wires 13..10
  // store from rC arrangement: slot d = amp m = d<<8|t; blocked addr
  //   S = (m>>3)<<13 | H<<3 | (m&7) = ((d<<5)|(t>>3))<<13 | H<<3 | (t&7)
  float2* dp = dst + (((size_t)H << 3) | (unsigned)(t & 7));
#pragma unroll
  for (int d = 0; d < 16; ++d) {
    float2 a;
    if (d & 1) a = make_float2(RE[d >> 1].y, IM[d >> 1].y);
    else       a = make_float2(RE[d >> 1].x, IM[d >> 1].x);
    dp[(((size_t)d << 5) | (unsigned)(t >> 3)) << 13] = a;
  }
}

// ---------------- pass B: gates on amp bits 12..21 (wires 9..0) ----------------
// block = chunk mid (grid 512): contiguous 64 KB. 256 threads x 32 amps.
// c = t&7 (j bits 0..2), u = t>>3 (5 bits). Round 1: d = h-bits 5..9 (wires 4..0);
// exchange d<->u; round 2: d = h-bits 0..4 (wires 9..5). Store NATURAL.
// LDS swizzle e = ((h<<3)|c) ^ (((h>>5)&3)<<3): conflict-free both directions.
__device__ __forceinline__ int pb_idx(unsigned h, unsigned c) {
  return (int)(((h << 3) | c) ^ (((h >> 5) & 3u) << 3));
}

__global__ __launch_bounds__(256, 4) void k_passB(const float2* __restrict__ src,
                                                  float2* __restrict__ dst,
                                                  const float* __restrict__ U,
                                                  int layer) {
  __shared__ float lds[8192];   // 32 KB
  const int t = threadIdx.x;
  const unsigned c = (unsigned)(t & 7), u = (unsigned)(t >> 3);   // u in 0..31
  const unsigned mid = blockIdx.x;
  const float2* sp = src + (((size_t)mid << 13) | c);
  v2f RE[16], IM[16];
#pragma unroll
  for (int d = 0; d < 32; ++d) {
    unsigned h = u | ((unsigned)d << 5);
    float2 a = sp[(size_t)h << 3];
    if (d & 1) { RE[d >> 1].y = a.x; IM[d >> 1].y = a.y; }
    else       { RE[d >> 1].x = a.x; IM[d >> 1].x = a.y; }
  }
  apply5p(RE, IM, U, layer, 4);              // wires 4..0
  __syncthreads();
#pragma unroll
  for (int d = 0; d < 32; ++d) {
    unsigned h = u | ((unsigned)d << 5);
    lds[pb_idx(h, c)] = (d & 1) ? RE[d >> 1].y : RE[d >> 1].x;
  }
  __syncthreads();
#pragma unroll
  for (int d = 0; d < 32; ++d) {
    unsigned h = (unsigned)d | (u << 5);
    float a = lds[pb_idx(h, c)];
    if (d & 1) RE[d >> 1].y = a; else RE[d >> 1].x = a;
  }
  __syncthreads();
#pragma unroll
  for (int d = 0; d < 32; ++d) {
    unsigned h = u | ((unsigned)d << 5);
    lds[pb_idx(h, c)] = (d & 1) ? IM[d >> 1].y : IM[d >> 1].x;
  }
  __syncthreads();
#pragma unroll
  for (int d = 0; d < 32; ++d) {
    unsigned h = (unsigned)d | (u << 5);
    float a = lds[pb_idx(h, c)];
    if (d & 1) IM[d >> 1].y = a; else IM[d >> 1].x = a;
  }
  apply5p(RE, IM, U, layer, 9);              // wires 9..5
#pragma unroll
  for (int d = 0; d < 32; ++d) {
    unsigned h = (unsigned)d | (u << 5);
    float2 a;
    if (d & 1) a = make_float2(RE[d >> 1].y, IM[d >> 1].y);
    else       a = make_float2(RE[d >> 1].x, IM[d >> 1].x);
    dst[((size_t)h << 12) | (mid << 3) | c] = a;   // natural layout
  }
}

// ---------------- last-layer pass B fused with expvals (final-CNOT sign trick) ----------------
// amp j: bits 0..2 = c, 3..11 = mid, 12..16 = d, 17..21 = u. invGray:
//  q=0..4:  sign = parity(u >> (4-q))         -> +/-Tot
//  q=5..9:  sign = parity(d >> (9-q)) ^ pu    -> +/-W_{9-q}
//  q=10..21: sign = y_{21-q} ^ pd ^ pu        -> +/-W0, y = suffix-XOR of (mid<<3|c)
__global__ __launch_bounds__(256, 4) void k_passB_ev(const float2* __restrict__ src,
                                                     const float* __restrict__ U,
                                                     float* __restrict__ partials,
                                                     int layer) {
  __shared__ float lds[8192];
  const int t = threadIdx.x;
  const unsigned c = (unsigned)(t & 7), u = (unsigned)(t >> 3);
  const unsigned mid = blockIdx.x;
  const float2* sp = src + (((size_t)mid << 13) | c);
  v2f RE[16], IM[16];
#pragma unroll
  for (int d = 0; d < 32; ++d) {
    unsigned h = u | ((unsigned)d << 5);
    float2 a = sp[(size_t)h << 3];
    if (d & 1) { RE[d >> 1].y = a.x; IM[d >> 1].y = a.y; }
    else       { RE[d >> 1].x = a.x; IM[d >> 1].x = a.y; }
  }
  apply5p(RE, IM, U, layer, 4);
  __syncthreads();
#pragma unroll
  for (int d = 0; d < 32; ++d) {
    unsigned h = u | ((unsigned)d << 5);
    lds[pb_idx(h, c)] = (d & 1) ? RE[d >> 1].y : RE[d >> 1].x;
  }
  __syncthreads();
#pragma unroll
  for (int d = 0; d < 32; ++d) {
    unsigned h = (unsigned)d | (u << 5);
    float a = lds[pb_idx(h, c)];
    if (d & 1) RE[d >> 1].y = a; else RE[d >> 1].x = a;
  }
  __syncthreads();
#pragma unroll
  for (int d = 0; d < 32; ++d) {
    unsigned h = u | ((unsigned)d << 5);
    lds[pb_idx(h, c)] = (d & 1) ? IM[d >> 1].y : IM[d >> 1].x;
  }
  __syncthreads();
#pragma unroll
  for (int d = 0; d < 32; ++d) {
    unsigned h = (unsigned)d | (u << 5);
    float a = lds[pb_idx(h, c)];
    if (d & 1) IM[d >> 1].y = a; else IM[d >> 1].x = a;
  }
  apply5p(RE, IM, U, layer, 9);

  // ---- expval epilogue: suffix-parity Walsh fold over 5 d-bits ----
  v2f PS[16];
#pragma unroll
  for (int k = 0; k < 16; ++k) PS[k] = RE[k] * RE[k] + IM[k] * IM[k];
  v2f S4[8], B4[8];
#pragma unroll
  for (int k = 0; k < 8; ++k) { S4[k] = PS[k] + PS[k + 8]; B4[k] = PS[k] - PS[k + 8]; }
  float Tot = 0.f, W4 = 0.f;
#pragma unroll
  for (int k = 0; k < 8; ++k) { Tot += S4[k].x + S4[k].y; W4 += B4[k].x + B4[k].y; }
  v2f B3[4];
#pragma unroll
  for (int k = 0; k < 4; ++k) B3[k] = B4[k] - B4[k + 4];
  float W3 = (B3[0].x + B3[0].y) + (B3[1].x + B3[1].y) + (B3[2].x + B3[2].y) + (B3[3].x + B3[3].y);
  v2f B2[2];
  B2[0] = B3[0] - B3[2]; B2[1] = B3[1] - B3[3];
  float W2 = (B2[0].x + B2[0].y) + (B2[1].x + B2[1].y);
  v2f B1 = B2[0] - B2[1];
  float W1 = B1.x + B1.y;
  float W0 = B1.x - B1.y;

  unsigned lowfull = (mid << 3) | c;
  unsigned y = lowfull; y ^= y >> 1; y ^= y >> 2; y ^= y >> 4; y ^= y >> 8;  // suffix-XOR
  unsigned pu = (unsigned)__popc(u) & 1u;
  float acc[22];
#pragma unroll
  for (int q = 0; q <= 4; ++q)
    acc[q] = ((unsigned)__popc(u >> (4 - q)) & 1u) ? -Tot : Tot;
  {
    float W[5] = {W0, W1, W2, W3, W4};
#pragma unroll
    for (int q = 5; q <= 9; ++q)
      acc[q] = pu ? -W[9 - q] : W[9 - q];
  }
#pragma unroll
  for (int q = 10; q <= 21; ++q)
    acc[q] = (((y >> (21 - q)) ^ pu) & 1u) ? -W0 : W0;

  __syncthreads();
  float* red = lds;                          // 4 waves * 23
  const int lane = t & 63, wv = t >> 6;
#pragma unroll
  for (int q = 0; q < 22; ++q) {
    float s = acc[q];
    for (int off = 32; off > 0; off >>= 1) s += __shfl_down(s, off, 64);
    if (lane == 0) red[wv * 23 + q] = s;
  }
  {
    float s = Tot;
    for (int off = 32; off > 0; off >>= 1) s += __shfl_down(s, off, 64);
    if (lane == 0) red[wv * 23 + 22] = s;
  }
  __syncthreads();
  if (t < 23) {
    float s = 0.f;
#pragma unroll
    for (int w = 0; w < 4; ++w) s += red[w * 23 + t];
    partials[t * 512 + mid] = s;
  }
}

__global__ void k_final(const float* __restrict__ partials, float* __restrict__ out) {
  __shared__ double res[32];
  const int t = threadIdx.x;
  const int r = t >> 3, l8 = t & 7;
  if (r < 23) {
    double s = 0.0;
    const float* p = partials + r * 512 + l8 * 64;
    for (int k = 0; k < 64; ++k) s += (double)p[k];
    for (int off = 4; off > 0; off >>= 1) s += __shfl_down(s, off, 8);
    if (l8 == 0) res[r] = s;
  }
  __syncthreads();
  if (t < 22) out[t] = (float)(res[t] / res[22]);  // normalization folded in
}

extern "C" void kernel_launch(void* const* d_in, const int* in_sizes, int n_in,
                              void* d_out, int out_size, void* d_ws, size_t ws_size,
                              hipStream_t stream) {
  const float* params = (const float*)d_in[0];   // [4][22][3]
  const float* sre = (const float*)d_in[1];      // [DIM]
  const float* sim = (const float*)d_in[2];      // [DIM]
  float* out = (float*)d_out;                    // [22]
  char* ws = (char*)d_ws;
  float* U = (float*)ws;                         // 88 * 8 floats
  float* partials = (float*)(ws + 4096);         // 23 * 512 floats
  float2* buf0 = (float2*)(ws + 131072);         // 32 MB  (blocked: A out / B in)
  float2* buf1 = buf0 + DIM;                     // 32 MB  (natural: B out / A in)

  k_gates<<<1, 128, 0, stream>>>(params, U);
  k_passA<<<1024, 256, 0, stream>>>(sre, sim, nullptr, buf0, U, 0, 1);
  k_passB<<<512, 256, 0, stream>>>(buf0, buf1, U, 0);
  for (int l = 1; l < 3; ++l) {
    k_passA<<<1024, 256, 0, stream>>>(nullptr, nullptr, buf1, buf0, U, l, 0);
    k_passB<<<512, 256, 0, stream>>>(buf0, buf1, U, l);
  }
  k_passA<<<1024, 256, 0, stream>>>(nullptr, nullptr, buf1, buf0, U, 3, 0);
  k_passB_ev<<<512, 256, 0, stream>>>(buf0, U, partials, 3);
  k_final<<<1, 256, 0, stream>>>(partials, out);
}